// Round 11
// baseline (216.413 us; speedup 1.0000x reference)
//
#include <hip/hip_runtime.h>
#include <math.h>

#define HH 960
#define WW 1280
#define NPIX (HH*WW)
#define BPR (WW/256)              // 5 col-segments per image row
#define NBLK_ROW (NPIX/256)       // 4800 row-mapped tiles (pre phase)
#define NBLK_MAIN (NPIX/(256*4))  // 1200: 4-row x 256-col tiles (main phase, R11 proven)

// workspace layout (bytes)
#define WS_POSE_OFF    0          // 16 floats
#define WS_S_OFF       128        // 3 slots x 32 floats (atomic JtWJ/JtR sums) = 384 B
#define WS_NX_OFF      512        // NPIX * 16 B = 19660800 B
#define WS_REC_OFF     19661312   // NPIX * 16 B = 19660800 B -> total ~39.3 MB

__device__ __forceinline__ int clampi(int v, int lo, int hi){ return v<lo?lo:(v>hi?hi:v); }

// pack two f32 -> one dword of 2 x f16 (lo = a, hi = b)
__device__ __forceinline__ float pack2h(float a, float b){
  _Float16 ha = (_Float16)a, hb = (_Float16)b;
  unsigned int u = ((unsigned int)__builtin_bit_cast(unsigned short, hb) << 16)
                 |  (unsigned int)__builtin_bit_cast(unsigned short, ha);
  return __builtin_bit_cast(float, u);
}
// unpack one dword of 2 x f16 -> (lo, hi) as f32
__device__ __forceinline__ float2 unpack2h(float p){
  unsigned int u = __builtin_bit_cast(unsigned int, p);
  _Float16 ha = __builtin_bit_cast(_Float16, (unsigned short)(u & 0xffffu));
  _Float16 hb = __builtin_bit_cast(_Float16, (unsigned short)(u >> 16));
  return make_float2((float)ha, (float)hb);
}

// ---------------- pre: pose copy + S zero + normals pack (image1) + gradient record (image0) -----
// R10 (kept): global depth-min/max invalidation dropped — verified bit-exact.
// R14 (kept): nx1 packed 16 B/pixel [d f32 | n f16x3 | rgb f16x3].
// R16 (kept): pose-independent RGB precompute hoisted: rec0 = {gx|gy x3, C1|C2} f16.
// R17: zero the 3 atomic S slots (re-armed every launch — re-poison safe).
__global__ __launch_bounds__(256) void k_pre(const float* __restrict__ depth1,
                                             const float* __restrict__ x0,
                                             const float* __restrict__ x1,
                                             const float* __restrict__ Kd,
                                             const float* __restrict__ pose_in,
                                             float* __restrict__ pose,
                                             float* __restrict__ S,
                                             float* __restrict__ nx1,
                                             float* __restrict__ rec0){
  int t = threadIdx.x;
  if (blockIdx.x == 0){
    if (t < 16) pose[t] = pose_in[t];
    else if (t >= 32 && t < 128) S[t-32] = 0.f;
  }
  int bid = blockIdx.x;
  int py = bid / BPR;
  int px = (bid % BPR)*256 + t;
  int idx = py*WW + px;
  float fx = Kd[0], fy = Kd[4], cx = Kd[2], cy = Kd[5];
  float invfx = 1.f/fx, invfy = 1.f/fy;

  // ---- image1: vertex-map sobel -> normal, pack with depth + color ----
  {
    float vx[3][3], vy[3][3], vz[3][3];
    #pragma unroll
    for (int dr = 0; dr < 3; dr++){
      int r = clampi(py + dr - 1, 0, HH-1);
      #pragma unroll
      for (int dc = 0; dc < 3; dc++){
        int c = clampi(px + dc - 1, 0, WW-1);
        float d = depth1[r*WW + c];
        vx[dr][dc] = ((float)c - cx)*invfx*d;
        vy[dr][dc] = ((float)r - cy)*invfy*d;
        vz[dr][dc] = d;
      }
    }
    float ax_ = (vx[0][2]-vx[0][0]) + 2.f*(vx[1][2]-vx[1][0]) + (vx[2][2]-vx[2][0]);
    float ay_ = (vy[0][2]-vy[0][0]) + 2.f*(vy[1][2]-vy[1][0]) + (vy[2][2]-vy[2][0]);
    float az_ = (vz[0][2]-vz[0][0]) + 2.f*(vz[1][2]-vz[1][0]) + (vz[2][2]-vz[2][0]);
    float bx_ = (vx[2][0]-vx[0][0]) + 2.f*(vx[2][1]-vx[0][1]) + (vx[2][2]-vx[0][2]);
    float by_ = (vy[2][0]-vy[0][0]) + 2.f*(vy[2][1]-vy[0][1]) + (vy[2][2]-vy[0][2]);
    float bz_ = (vz[2][0]-vz[0][0]) + 2.f*(vz[2][1]-vz[0][1]) + (vz[2][2]-vz[0][2]);
    float nx = ay_*bz_ - az_*by_;
    float ny = az_*bx_ - ax_*bz_;
    float nz = ax_*by_ - ay_*bx_;
    float nrm = sqrtf(nx*nx + ny*ny + nz*nz) + 1e-8f;
    float rn  = __builtin_amdgcn_rcpf(nrm);
    nx *= rn; ny *= rn; nz *= rn;
    float dcen = vz[1][1];
    const float* q = &x1[idx*3];
    float4 a;
    a.x = dcen;
    a.y = pack2h(nx, ny);
    a.z = pack2h(nz, q[0]);
    a.w = pack2h(q[1], q[2]);
    ((float4*)nx1)[idx] = a;
  }

  // ---- image0: normalized sobel gradients + center-color dots (pose-independent) ----
  {
    int rm = clampi(py-1, 0, HH-1), rp = clampi(py+1, 0, HH-1);
    int cm = clampi(px-1, 0, WW-1), cp = clampi(px+1, 0, WW-1);
    const float* p00 = &x0[(rm*WW+cm)*3];
    const float* p01 = &x0[(rm*WW+px)*3];
    const float* p02 = &x0[(rm*WW+cp)*3];
    const float* p10 = &x0[(py*WW+cm)*3];
    const float* p11 = &x0[(py*WW+px)*3];
    const float* p12 = &x0[(py*WW+cp)*3];
    const float* p20 = &x0[(rp*WW+cm)*3];
    const float* p21 = &x0[(rp*WW+px)*3];
    const float* p22 = &x0[(rp*WW+cp)*3];
    float gx[3], gy[3];
    float C1 = 0.f, C2 = 0.f;
    #pragma unroll
    for (int ch = 0; ch < 3; ch++){
      float a00 = p00[ch], a01 = p01[ch], a02 = p02[ch];
      float a10 = p10[ch],                a12 = p12[ch];
      float a20 = p20[ch], a21 = p21[ch], a22 = p22[ch];
      float dx = (a02-a00) + 2.f*(a12-a10) + (a22-a20);
      float dy = (a20-a00) + 2.f*(a21-a01) + (a22-a02);
      float rinv = __builtin_amdgcn_rsqf(dx*dx + dy*dy + 1e-8f);
      gx[ch] = dx*rinv; gy[ch] = dy*rinv;
      float c = p11[ch];
      C1 += gx[ch]*c; C2 += gy[ch]*c;
    }
    float4 r;
    r.x = pack2h(gx[0], gy[0]);
    r.y = pack2h(gx[1], gy[1]);
    r.z = pack2h(gx[2], gy[2]);
    r.w = pack2h(C1, C2);
    ((float4*)rec0)[idx] = r;
  }
}

// ---------------- fused per-pixel ICP + RGB accumulation (no LDS tile, XCD swizzle) ----------
// R11 geometry + R14 packed gathers + R16 hoisted gradients.
// R17: block partials atomicAdd'ed straight into S[it] (27 floats) — no partial buffer,
// k_solve's 134 KB cross-XCD read phase disappears. Dispatch boundary orders S vs k_solve
// (no fence needed — the R15 mistake). Float-atomic accumulation HW-validated by R15
// (ran 222us, absmax 0.0).
__global__ __launch_bounds__(256) void k_main(const float* __restrict__ depth0,
                                              const float* __restrict__ rec0,
                                              const float* __restrict__ nx1,
                                              const float* __restrict__ Kd,
                                              const float* __restrict__ pose,
                                              float* __restrict__ S,
                                              int it){
  int t = threadIdx.x;
  // XCD-aware swizzle: contiguous 150-tile (120-row) band per XCD (R6: FETCH 92->29 MB)
  int bid = (blockIdx.x & 7)*(NBLK_MAIN/8) + (blockIdx.x >> 3);
  int pr = bid / BPR;
  int cs = bid % BPR;
  int py0 = pr*4;
  int px = cs*256 + t;

  int idx0 = py0*WW + px;
  float d0v[4];
  #pragma unroll
  for (int kp = 0; kp < 4; kp++) d0v[kp] = depth0[idx0 + kp*WW];

  float fx = Kd[0], fy = Kd[4], cx = Kd[2], cy = Kd[5];
  float inv_fx = 1.f/fx, inv_fy = 1.f/fy;
  float R00=pose[0], R01=pose[1], R02=pose[2],  tx=pose[3];
  float R10=pose[4], R11=pose[5], R12=pose[6],  ty=pose[7];
  float R20=pose[8], R21=pose[9], R22=pose[10], tz=pose[11];

  float acc[27];
  #pragma unroll
  for (int k = 0; k < 27; k++) acc[k] = 0.f;

  const float4* nx4 = (const float4*)nx1;
  const float4* rc4 = (const float4*)rec0;

  #pragma unroll
  for (int kp = 0; kp < 4; kp++){
    int py = py0 + kp;

    float d0 = d0v[kp];
    float4 rv = rc4[idx0 + kp*WW];      // own-pixel gradient record (coalesced)
    bool m0 = d0 > 0.f;
    float v0x = ((float)px - cx)*inv_fx*d0;
    float v0y = ((float)py - cy)*inv_fy*d0;
    float v0z = d0;
    float X = R00*v0x + R01*v0y + R02*v0z + tx;
    float Y = R10*v0x + R11*v0y + R12*v0z + ty;
    float Z = R20*v0x + R21*v0y + R22*v0z + tz;
    // 1/Z via rcp + one Newton step (drives u,v indices)
    float invZ = __builtin_amdgcn_rcpf(Z);
    invZ = invZ*(2.0f - Z*invZ);
    float u = X*invZ*fx + cx;
    float v = Y*invZ*fy + cy;
    bool inview = (u > 0.f) && (u < (float)(WW-1)) && (v > 0.f) && (v < (float)(HH-1)) && (Z > 0.f);

    float uc = fminf(fmaxf(u, 0.f), (float)(WW-1));
    float vc = fminf(fmaxf(v, 0.f), (float)(HH-1));
    float u0f = floorf(uc), v0f = floorf(vc);
    float wu = uc - u0f, wv = vc - v0f;
    int u0i = clampi((int)u0f, 0, WW-1);
    int v0i = clampi((int)v0f, 0, HH-1);
    int u1i = min(u0i + 1, WW-1);
    int v1i = min(v0i + 1, HH-1);
    int i00 = v0i*WW + u0i, i01 = v0i*WW + u1i, i10 = v1i*WW + u0i, i11 = v1i*WW + u1i;
    float w00 = (1.f-wu)*(1.f-wv), w01 = wu*(1.f-wv), w10 = (1.f-wu)*wv, w11 = wu*wv;

    float4 p00 = nx4[i00], p01 = nx4[i01], p10 = nx4[i10], p11v = nx4[i11];

    // unpack: .x = d (f32), .y = nx|ny, .z = nz|r, .w = g|b
    float2 nab00 = unpack2h(p00.y), nzr00 = unpack2h(p00.z);
    float2 nab01 = unpack2h(p01.y), nzr01 = unpack2h(p01.z);
    float2 nab10 = unpack2h(p10.y), nzr10 = unpack2h(p10.z);
    float2 nab11 = unpack2h(p11v.y), nzr11 = unpack2h(p11v.z);

    // factored vertex interpolation (d exact f32)
    float t0 = w00*p00.x, t1 = w01*p01.x, t2 = w10*p10.x, t3 = w11*p11v.x;
    float u0c = ((float)u0i - cx)*inv_fx, u1c = ((float)u1i - cx)*inv_fx;
    float v0c = ((float)v0i - cy)*inv_fy, v1c = ((float)v1i - cy)*inv_fy;
    float s2 = (t0+t1)+(t2+t3);
    float s0 = u0c*(t0+t2) + u1c*(t1+t3);
    float s1 = v0c*(t0+t1) + v1c*(t2+t3);
    float nx = nab00.x*w00 + nab01.x*w01 + nab10.x*w10 + nab11.x*w11;
    float ny = nab00.y*w00 + nab01.y*w01 + nab10.y*w10 + nab11.y*w11;
    float nz = nzr00.x*w00 + nzr01.x*w01 + nzr10.x*w10 + nzr11.x*w11;

    float dfx = X - s0, dfy = Y - s1, dfz = Z - s2;
    bool valid = inview && m0 && (s2 > 0.f) && (dfx*dfx + dfy*dfy + dfz*dfz < 0.01f);
    float res = 0.f;
    float J[6] = {0.f,0.f,0.f,0.f,0.f,0.f};
    if (valid){
      res = nx*dfx + ny*dfy + nz*dfz;
      J[0] = Y*nz - Z*ny;
      J[1] = Z*nx - X*nz;
      J[2] = X*ny - Y*nx;
      J[3] = nx; J[4] = ny; J[5] = nz;
    }
    float axv = fabsf(res);
    float rho = (axv <= 0.02f) ? axv*axv : (0.04f*axv - 0.0004f);
    float xs  = (axv < 1e-8f) ? 1.f : axv;
    float hw  = sqrtf(rho + 1e-16f) * __builtin_amdgcn_rcpf(xs);
    float wr  = hw*res;
    float wJ[6];
    #pragma unroll
    for (int i = 0; i < 6; i++) wJ[i] = hw*J[i];
    {
      int k = 0;
      #pragma unroll
      for (int i = 0; i < 6; i++)
        #pragma unroll
        for (int j = i; j < 6; j++)
          acc[k++] += wJ[i]*wJ[j];
      #pragma unroll
      for (int i = 0; i < 6; i++) acc[21+i] += wJ[i]*wr;
    }

    if (inview && m0){
      float2 gb00 = unpack2h(p00.w), gb01 = unpack2h(p01.w);
      float2 gb10 = unpack2h(p10.w), gb11 = unpack2h(p11v.w);
      float xw0 = nzr00.y*w00 + nzr01.y*w01 + nzr10.y*w10 + nzr11.y*w11;
      float xw1 = gb00.x*w00 + gb01.x*w01 + gb10.x*w10 + gb11.x*w11;
      float xw2 = gb00.y*w00 + gb01.y*w01 + gb10.y*w10 + gb11.y*w11;

      // hoisted gradients: g_ch = (gx,gy), C1 = dot(gx, x0), C2 = dot(gy, x0)
      float2 g0 = unpack2h(rv.x), g1 = unpack2h(rv.y), g2 = unpack2h(rv.z), cc = unpack2h(rv.w);
      float ga  = g0.x*g0.x + g1.x*g1.x + g2.x*g2.x;
      float gbv = g0.x*g0.y + g1.x*g1.y + g2.x*g2.y;
      float gc2 = g0.y*g0.y + g1.y*g1.y + g2.y*g2.y;
      float rx  = g0.x*xw0 + g1.x*xw1 + g2.x*xw2 - cc.x;
      float ry  = g0.y*xw0 + g1.y*xw1 + g2.y*xw2 - cc.y;
      ga *= 1e-6f; gbv *= 1e-6f; gc2 *= 1e-6f; rx *= 1e-6f; ry *= 1e-6f;

      float invD = __builtin_amdgcn_rcpf(d0), invD2 = invD*invD;
      float xy = v0x*v0y;
      float Jx[6] = { fx*(-invD2*xy), fx*(1.f + v0x*v0x*invD2), fx*(-v0y*invD), fx*invD, 0.f, fx*(-invD2*v0x) };
      float Jy[6] = { fy*(-1.f - invD2*v0y*v0y), fy*(xy*invD2), fy*(v0x*invD), 0.f, fy*invD, fy*(-invD2*v0y) };
      float P[6], Q[6];
      #pragma unroll
      for (int i = 0; i < 6; i++){ P[i] = ga*Jx[i] + gbv*Jy[i]; Q[i] = gbv*Jx[i] + gc2*Jy[i]; }
      int k = 0;
      #pragma unroll
      for (int i = 0; i < 6; i++)
        #pragma unroll
        for (int j = i; j < 6; j++)
          acc[k++] += Jx[j]*P[i] + Jy[j]*Q[i];
      #pragma unroll
      for (int i = 0; i < 6; i++) acc[21+i] += Jx[i]*rx + Jy[i]*ry;
    }
  }

  // block reduction: wave shfl -> LDS -> 27 atomic adds into S[it]
  __shared__ float lds[108];
  int lane = t & 63;
  int wid  = t >> 6;
  #pragma unroll
  for (int k = 0; k < 27; k++){
    float vv = acc[k];
    vv += __shfl_down(vv, 32); vv += __shfl_down(vv, 16); vv += __shfl_down(vv, 8);
    vv += __shfl_down(vv, 4);  vv += __shfl_down(vv, 2);  vv += __shfl_down(vv, 1);
    if (lane == 0) lds[wid*27 + k] = vv;
  }
  __syncthreads();
  if (t < 27)
    atomicAdd(&S[it*32 + t], lds[t] + lds[27+t] + lds[54+t] + lds[81+t]);
}

// ---------------- per-iteration: damped 6x6 solve from S[it] + pose update (double) ----------
// R17: reads 27 floats instead of 134 KB of cross-XCD partials.
__global__ __launch_bounds__(64) void k_solve(const float* __restrict__ S,
                                              float* __restrict__ pose,
                                              float* __restrict__ outp,
                                              int it){
  if (threadIdx.x != 0) return;
  double s[27];
  #pragma unroll
  for (int k = 0; k < 27; k++) s[k] = (double)S[it*32 + k];
  double Hm[6][6], b[6];
  {
    int k = 0;
    for (int i = 0; i < 6; i++)
      for (int j = i; j < 6; j++){ Hm[i][j] = s[k]; Hm[j][i] = s[k]; k++; }
    for (int i = 0; i < 6; i++) b[i] = s[21+i];
  }
  double tr = Hm[0][0]+Hm[1][1]+Hm[2][2]+Hm[3][3]+Hm[4][4]+Hm[5][5];
  for (int i = 0; i < 6; i++) Hm[i][i] += tr*0.001;
  double A[6][7];
  for (int i = 0; i < 6; i++){
    for (int j = 0; j < 6; j++) A[i][j] = Hm[i][j];
    A[i][6] = b[i];
  }
  for (int c = 0; c < 6; c++){
    int piv = c; double best = fabs(A[c][c]);
    for (int r = c+1; r < 6; r++){ double a = fabs(A[r][c]); if (a > best){ best = a; piv = r; } }
    if (piv != c)
      for (int j = 0; j < 7; j++){ double tv = A[c][j]; A[c][j] = A[piv][j]; A[piv][j] = tv; }
    double inv = 1.0/A[c][c];
    for (int r = 0; r < 6; r++){
      if (r == c) continue;
      double f = A[r][c]*inv;
      for (int j = c; j < 7; j++) A[r][j] -= f*A[c][j];
    }
  }
  double xi[6];
  for (int i = 0; i < 6; i++) xi[i] = A[i][6]/A[i][i];
  double wx = -xi[0], wy = -xi[1], wz = -xi[2];
  double th2 = wx*wx + wy*wy + wz*wz;
  if (th2 < 1e-30) th2 = 1e-30;
  double th = sqrt(th2);
  double dR[3][3];
  if (th <= 1e-10){
    dR[0][0]=1; dR[0][1]=0; dR[0][2]=0;
    dR[1][0]=0; dR[1][1]=1; dR[1][2]=0;
    dR[2][0]=0; dR[2][1]=0; dR[2][2]=1;
  } else {
    double sa = sin(th)/th;
    double sb = (1.0 - cos(th))/th2;
    double Wm[3][3] = {{0,-wz,wy},{wz,0,-wx},{-wy,wx,0}};
    double W2[3][3];
    for (int i = 0; i < 3; i++)
      for (int j = 0; j < 3; j++)
        W2[i][j] = Wm[i][0]*Wm[0][j] + Wm[i][1]*Wm[1][j] + Wm[i][2]*Wm[2][j];
    for (int i = 0; i < 3; i++)
      for (int j = 0; j < 3; j++)
        dR[i][j] = (i==j ? 1.0 : 0.0) + sa*Wm[i][j] + sb*W2[i][j];
  }
  double dt[3];
  for (int i = 0; i < 3; i++)
    dt[i] = -(dR[i][0]*xi[3] + dR[i][1]*xi[4] + dR[i][2]*xi[5]);
  double Ro[3][3], to[3];
  for (int i = 0; i < 3; i++){
    for (int j = 0; j < 3; j++) Ro[i][j] = (double)pose[i*4+j];
    to[i] = (double)pose[i*4+3];
  }
  double Rn[3][3], tn[3];
  for (int i = 0; i < 3; i++){
    for (int j = 0; j < 3; j++)
      Rn[i][j] = dR[i][0]*Ro[0][j] + dR[i][1]*Ro[1][j] + dR[i][2]*Ro[2][j];
    tn[i] = dR[i][0]*to[0] + dR[i][1]*to[1] + dR[i][2]*to[2] + dt[i];
  }
  float o16[16];
  for (int i = 0; i < 3; i++){
    for (int j = 0; j < 3; j++) o16[i*4+j] = (float)Rn[i][j];
    o16[i*4+3] = (float)tn[i];
  }
  o16[12] = 0.f; o16[13] = 0.f; o16[14] = 0.f; o16[15] = 1.f;
  for (int k = 0; k < 16; k++){ pose[k] = o16[k]; outp[k] = o16[k]; }
}

extern "C" void kernel_launch(void* const* d_in, const int* in_sizes, int n_in,
                              void* d_out, int out_size, void* d_ws, size_t ws_size,
                              hipStream_t stream) {
  const float* pose10 = (const float*)d_in[0];
  const float* depth0 = (const float*)d_in[1];
  const float* depth1 = (const float*)d_in[2];
  const float* x0     = (const float*)d_in[3];
  const float* x1     = (const float*)d_in[4];
  const float* Kd     = (const float*)d_in[5];
  char* ws = (char*)d_ws;
  float* pose = (float*)(ws + WS_POSE_OFF);
  float* S    = (float*)(ws + WS_S_OFF);
  float* nx1  = (float*)(ws + WS_NX_OFF);
  float* rec0 = (float*)(ws + WS_REC_OFF);
  float* outp = (float*)d_out;

  hipLaunchKernelGGL(k_pre, dim3(NBLK_ROW), dim3(256), 0, stream,
                     depth1, x0, x1, Kd, pose10, pose, S, nx1, rec0);
  for (int it = 0; it < 3; it++){
    hipLaunchKernelGGL(k_main,  dim3(NBLK_MAIN), dim3(256), 0, stream,
                       depth0, rec0, nx1, Kd, pose, S, it);
    hipLaunchKernelGGL(k_solve, dim3(1), dim3(64), 0, stream, S, pose, outp, it);
  }
}